// Round 7
// baseline (155.536 us; speedup 1.0000x reference)
//
#include <hip/hip_runtime.h>

#define DIM   1024
#define NG    8
#define NBLK  128                 // proven R13/R16 geometry
#define TPB   512                 // 8 waves/block
#define WAVES (TPB / 64)
#define ROWS_PER_BLK WAVES        // RPW = 1: one row per wave
#define SCALE    1.45f            // upper bound on spectral radius (semicircle ~1.414)
#define INVSCALE (1.0f / SCALE)
#define CTOL  5e-3f               // same truncation (absmax 9.155e-5, stable tripwire)
#define KMAX  12
#define FSTRIDE 16                // flags padded to 64B (16 u32) each

typedef unsigned long long u64;
union f2u { float2 f; u64 u; };

// R17 = R16 protocol (8B agent elements, producer store-ack before flag,
// concentrated wave0 poll, LDS staging, s_sleep backoff) with three serial
// micro-terms removed from the per-phase chain:
//  (1) wave0-stages-all: on detect, wave0 itself issues the 16 vector loads
//      (pattern vsrc[p*64+lane] == its own matvec layout, so it consumes the
//      registers directly), ds_writes smemV, RELEASE-stores ready. Waves 1-7
//      wake straight into ds_read -- no per-wave stage loads, no
//      __syncthreads in the k-loop at all. WAR is safe barrier-free: wave0
//      overwrites smemV at phase p+1 only after detecting ALL flags >= p+1,
//      which requires this block's waves published p+1, which data-depends
//      on their ds_reads of phase p.
//  (2) deferred ack: publish split into store -> tail acc-FMAs ->
//      waitcnt(0)+wdone+flag; tail VALU hides inside the store-ack RTT.
//  (3) double-buffered G (anext): all waves prefetch gate g+1's row right
//      AFTER the k==1 commit; loads drain under the k==2 detect window
//      (wave0's first poll waitcnt absorbs them within one RTT; waves 1-7
//      have no vmem until their k==2 publish, a full phase later). pendG
//      and the waves-1-7 boundary prefetch are gone; zero boundary exposure.

__global__ __launch_bounds__(TPB) void qsim_kernel(
    const float* __restrict__ feat,
    const float* __restrict__ theta,
    const float* __restrict__ gens,
    float*       __restrict__ out,
    u64*         __restrict__ vbuf0,
    u64*         __restrict__ vbuf1,
    unsigned*    __restrict__ flags)
{
  const int tid  = threadIdx.x;
  const int lane = tid & 63;
  const int wid  = tid >> 6;                       // 0..7
  const int bid  = blockIdx.x;
  const int row  = bid * ROWS_PER_BLK + wid;       // this wave's row (RPW=1)

  __shared__ float2   smemV[DIM];                  // 8KB staged vector
  __shared__ float    red[WAVES];
  __shared__ unsigned wdone;                       // monotone publish counter
  __shared__ unsigned ready;                       // monotone wake word

  // ---- gate-0 G row first: HBM latency overlaps the norm phase ----
  float a[16];
  {
    const float* Gr = gens + (size_t)row * DIM;
    #pragma unroll
    for (int p = 0; p < 16; ++p) a[p] = Gr[p * 64 + lane];
  }

  if (tid == 0) { wdone = 0; ready = 0; }
  {
    float f0 = feat[tid], f1 = feat[tid + TPB];
    float s = f0 * f0 + f1 * f1;
    #pragma unroll
    for (int mm = 1; mm < 64; mm <<= 1) s += __shfl_xor(s, mm);
    if (lane == 0) red[wid] = s;
  }
  __syncthreads();                                  // init only
  float tot = 0.f;
  #pragma unroll
  for (int i = 0; i < WAVES; ++i) tot += red[i];
  const float inv = 1.0f / sqrtf(tot);

  float pr = feat[row] * inv;
  float pi = 0.f;

  unsigned pub = 0;   // completed publishes (lock-stepped across all waves/blocks)

  auto pub_store = [&](float sr, float si) {
    u64* dst = ((pub + 1) & 1) ? vbuf1 : vbuf0;
    if (lane == 0) {
      f2u x; x.f = make_float2(sr, si);
      __hip_atomic_store(dst + row, x.u,
                         __ATOMIC_RELAXED, __HIP_MEMORY_SCOPE_AGENT);
    }
  };
  auto pub_commit = [&]() {
    __builtin_amdgcn_sched_barrier(0);
    __builtin_amdgcn_s_waitcnt(0);    // ack: wave's data store is at the LLC now
    __builtin_amdgcn_sched_barrier(0);
    ++pub;
    if (lane == 0) {
      unsigned old = atomicAdd(&wdone, 1u);         // LDS, monotone
      if (old == WAVES * pub - 1) {                 // block's last publisher
        __hip_atomic_store(flags + bid * FSTRIDE, pub,
                           __ATOMIC_RELAXED, __HIP_MEMORY_SCOPE_AGENT);
      }
    }
  };

  for (int g = 0; g < NG; ++g) {
    // ---- Chebyshev coefficients: J_k(|z|), downward Miller in fp64 ----
    const float  th = theta[g];
    const double z  = (double)th * (double)SCALE;
    const double az = fmax(fabs(z), 1e-6);
    const float  sg = (th < 0.f) ? -1.f : 1.f;      // J_k(z)=sg^k J_k(|z|)

    double bv[19];
    bv[18] = 1e-30;
    bv[17] = (36.0 / az) * 1e-30;
    #pragma unroll
    for (int k = 17; k >= 1; --k)
      bv[k - 1] = (2.0 * (double)k / az) * bv[k] - bv[k + 1];
    double S = bv[0];
    #pragma unroll
    for (int k = 2; k <= 18; k += 2) S += 2.0 * bv[k];
    const double invS = 1.0 / S;

    // coeffs to float REGISTERS (constant indices only from here on)
    float jc[KMAX + 2];
    #pragma unroll
    for (int k = 0; k <= KMAX + 1; ++k) jc[k] = (float)(bv[k] * invS);

    int m = KMAX; bool found = false;
    #pragma unroll
    for (int k = 1; k <= KMAX; ++k) {
      if (!found && (double)(k + 1) > az &&
          fabs(bv[k + 1] * invS) < (double)CTOL) { m = k; found = true; }
    }
    // m identical on every wave/block -> uniform phase count

    float accr = jc[0] * pr, acci = jc[0] * pi;
    float wm1r = pr, wm1i = pi, wm2r = 0.f, wm2i = 0.f;
    float anext[16];                                // gate g+1 rows (item 3)

    #pragma unroll
    for (int k = 1; k <= KMAX; ++k) {               // fully unrolled
      if (k > m) break;

      // ---- consume full w_{k-1} ----
      float2 v[16];
      if (g == 0 && k == 1) {
        // psi_0 rebuilt locally: no publish/wait phase needed
        #pragma unroll
        for (int p = 0; p < 16; ++p)
          v[p] = make_float2(feat[p * 64 + lane] * inv, 0.f);
      } else {
        if (wid == 0) {
          // 4-deep software-pipelined flag poll with s_sleep backoff
          unsigned a0 = __hip_atomic_load(flags + lane * FSTRIDE,
                                          __ATOMIC_RELAXED, __HIP_MEMORY_SCOPE_AGENT);
          unsigned b0 = __hip_atomic_load(flags + (lane + 64) * FSTRIDE,
                                          __ATOMIC_RELAXED, __HIP_MEMORY_SCOPE_AGENT);
          unsigned a1 = __hip_atomic_load(flags + lane * FSTRIDE,
                                          __ATOMIC_RELAXED, __HIP_MEMORY_SCOPE_AGENT);
          unsigned b1 = __hip_atomic_load(flags + (lane + 64) * FSTRIDE,
                                          __ATOMIC_RELAXED, __HIP_MEMORY_SCOPE_AGENT);
          unsigned a2 = __hip_atomic_load(flags + lane * FSTRIDE,
                                          __ATOMIC_RELAXED, __HIP_MEMORY_SCOPE_AGENT);
          unsigned b2 = __hip_atomic_load(flags + (lane + 64) * FSTRIDE,
                                          __ATOMIC_RELAXED, __HIP_MEMORY_SCOPE_AGENT);
          unsigned a3 = __hip_atomic_load(flags + lane * FSTRIDE,
                                          __ATOMIC_RELAXED, __HIP_MEMORY_SCOPE_AGENT);
          unsigned b3 = __hip_atomic_load(flags + (lane + 64) * FSTRIDE,
                                          __ATOMIC_RELAXED, __HIP_MEMORY_SCOPE_AGENT);
          for (;;) {
            // wrap-safe monotone >=; 0xAAAAAAAA poison reads "not ready"
            if (__all((((int)(a0 - pub) >= 0) & ((int)(b0 - pub) >= 0)))) break;
            __builtin_amdgcn_s_sleep(1);            // ~64cy backoff
            a0 = a1; b0 = b1; a1 = a2; b1 = b2; a2 = a3; b2 = b3;
            a3 = __hip_atomic_load(flags + lane * FSTRIDE,
                                   __ATOMIC_RELAXED, __HIP_MEMORY_SCOPE_AGENT);
            b3 = __hip_atomic_load(flags + (lane + 64) * FSTRIDE,
                                   __ATOMIC_RELAXED, __HIP_MEMORY_SCOPE_AGENT);
          }
          // stage the WHOLE vector: wave0's load pattern == its matvec layout
          const u64* vsrc = (pub & 1) ? vbuf1 : vbuf0;
          f2u x[16];
          #pragma unroll
          for (int p = 0; p < 16; ++p)
            x[p].u = __hip_atomic_load(vsrc + p * 64 + lane,
                                       __ATOMIC_RELAXED, __HIP_MEMORY_SCOPE_AGENT);
          #pragma unroll
          for (int p = 0; p < 16; ++p) smemV[p * 64 + lane] = x[p].f;
          // release: ds_writes (and loads) ordered before the wake word
          __hip_atomic_store(&ready, pub, __ATOMIC_RELEASE,
                             __HIP_MEMORY_SCOPE_WORKGROUP);
          #pragma unroll
          for (int p = 0; p < 16; ++p) v[p] = x[p].f;   // direct consume
        } else {
          while ((int)(__hip_atomic_load(&ready, __ATOMIC_ACQUIRE,
                                         __HIP_MEMORY_SCOPE_WORKGROUP) - pub) < 0) {
            __builtin_amdgcn_s_sleep(1);            // ~64cy backoff
          }
          #pragma unroll
          for (int p = 0; p < 16; ++p) v[p] = smemV[p * 64 + lane];
        }
      }

      // ---- y = G * w_{k-1} (own row) ----
      float yr = 0.f, yi = 0.f;
      #pragma unroll
      for (int p = 0; p < 16; ++p) {
        yr = fmaf(a[p], v[p].x, yr);
        yi = fmaf(a[p], v[p].y, yi);
      }
      #pragma unroll
      for (int mm = 1; mm < 64; mm <<= 1) {
        yr += __shfl_xor(yr, mm);
        yi += __shfl_xor(yi, mm);
      }

      // ---- w_k = (k==1) ? xh*w_0 : 2*xh*w_{k-1} - w_{k-2} ----
      const float ur = yr * INVSCALE;
      const float ui = yi * INVSCALE;
      const float wkr = (k == 1) ? ur : fmaf(2.f, ur, -wm2r);
      const float wki = (k == 1) ? ui : fmaf(2.f, ui, -wm2i);

      const bool last = (k == m);
      if (!last) pub_store(wkr, wki);   // store issues; ack deferred below

      // ---- acc += c_k * w_k,  c_k = 2*(-i*sg)^k * J_k(|z|) ----
      // (runs between store and ack: hidden inside the store-ack RTT)
      {
        const float j2  = 2.f * jc[k];              // register (constant k)
        const float sj2 = sg * j2;
        if ((k & 3) == 0) {
          accr = fmaf(j2, wkr, accr);
          acci = fmaf(j2, wki, acci);
        } else if ((k & 3) == 1) {
          accr = fmaf( sj2, wki, accr);
          acci = fmaf(-sj2, wkr, acci);
        } else if ((k & 3) == 2) {
          accr = fmaf(-j2, wkr, accr);
          acci = fmaf(-j2, wki, acci);
        } else {
          accr = fmaf(-sj2, wki, accr);
          acci = fmaf( sj2, wkr, acci);
        }
      }

      if (!last) pub_commit();          // waitcnt(0) + wdone + flag

      // ---- gate g+1 G prefetch: issued AFTER the k==1 commit so the ack
      // never waits on it; drains under the k==2 detect window ----
      if (k == 1 && g < NG - 1) {
        const float* Gr = gens + (size_t)(g + 1) * DIM * DIM
                               + (size_t)row * DIM;
        #pragma unroll
        for (int p = 0; p < 16; ++p) anext[p] = Gr[p * 64 + lane];
      }

      if (last) {
        if (g < NG - 1) {
          pub_store(accr, acci);                    // psi_{g+1}
          pub_commit();
        }
      } else {
        wm2r = wm1r; wm2i = wm1i;
        wm1r = wkr;  wm1i = wki;
      }
    }

    if (g < NG - 1) {
      #pragma unroll
      for (int p = 0; p < 16; ++p) a[p] = anext[p]; // swap in next gate's row
    }
    pr = accr; pi = acci;
  }

  if (lane == 0) out[row] = pr * pr + pi * pi;
}

extern "C" void kernel_launch(void* const* d_in, const int* in_sizes, int n_in,
                              void* d_out, int out_size, void* d_ws, size_t ws_size,
                              hipStream_t stream) {
  const float* feat  = (const float*)d_in[0];
  const float* theta = (const float*)d_in[1];
  const float* gens  = (const float*)d_in[2];
  float* out = (float*)d_out;

  // layout: flags 128 x 64B (8KB) | vbuf0 (8KB) | vbuf1 (8KB) = 24KB
  // no memset: wrap-safe flag compare treats the 0xAA poison as "not ready"
  unsigned* flags = (unsigned*)d_ws;
  u64* vbuf0 = (u64*)((char*)d_ws + 8192);
  u64* vbuf1 = (u64*)((char*)d_ws + 8192 + (size_t)DIM * sizeof(u64));

  qsim_kernel<<<dim3(NBLK), dim3(TPB), 0, stream>>>(
      feat, theta, gens, out, vbuf0, vbuf1, flags);
}

// Round 8
// 144.210 us; speedup vs baseline: 1.0785x; 1.0785x over previous
//
#include <hip/hip_runtime.h>

#define DIM   1024
#define NG    8
#define NBLK  128
#define TPB   512
#define WAVES (TPB / 64)          // 8
#define SCALE    1.45f            // upper bound on spectral radius (semicircle ~1.414)
#define INVSCALE (1.0f / SCALE)
#define CTOL  5e-3f               // same truncation (absmax 9.155e-5, stable tripwire)
#define KMAX  12
#define SEGW  (2 * WAVES)         // 16 u64 words per block segment (128B)

typedef unsigned long long u64;

// R18: fan-in publish -- the segment IS the flag.
// R16/R17 pinned the phase floor at ~2.4us = THREE serial LLC RTTs
// (store-ack, flag-propagate+detect, stage load). R11/R12 showed naive
// no-ack fails because 1024 independent 8B stores commit over an unbounded
// window and consumers retry against it. R18 removes two RTTs while fixing
// that: each block aggregates its 8 elements in LDS (no RTT), then the
// LAST wave (wdone==8 detector) stores the whole 128B segment -- 16 u64
// words {f32 | u32 seq} -- as ONE coalesced store instruction. The commit
// window collapses to 1-2 cache lines at once. Consumers: wave0-only polls
// all 128 segments (32x8B per lane, s_sleep(2) backoff), validates the
// embedded seqs (8B single-copy atomic), ds_writes to smemV, release-stores
// ready. The poll IS the data load: no ack, no flags, no separate stage.
// Chain: LDS agg (~150cy) -> one-way commit -> poll sweep -> LDS -> matvec
// ~= 1.5 RTTs.
// WAR safety (same induction the flag protocol used, carried by seqs):
// block Y stores phase p+1 only after consuming p <= every block's segment
// p committed <= every closer's smemPub reads retired (data dependency) and
// every block consumed p-1 -- so same-parity overwrites post-date all reads.
// smemPub WAR: wave W rewrites smemPub[W] at p+1 only after consuming p,
// which requires its own block's closer-of-p stores committed, which
// data-depend on the closer's smemPub reads. Poison 0xAAAAAAAA never
// matches a real seq (<= ~40); harness re-poisons workspace per iteration.

__device__ __forceinline__ u64 packw(float v, unsigned seq) {
  union { float f; unsigned u; } c; c.f = v;
  return ((u64)seq << 32) | (u64)c.u;
}
__device__ __forceinline__ float unpackf(u64 x) {
  union { unsigned u; float f; } c; c.u = (unsigned)x;
  return c.f;
}

__global__ __launch_bounds__(TPB) void qsim_kernel(
    const float* __restrict__ feat,
    const float* __restrict__ theta,
    const float* __restrict__ gens,
    float*       __restrict__ out,
    u64*         __restrict__ vbuf0,
    u64*         __restrict__ vbuf1)
{
  const int tid  = threadIdx.x;
  const int lane = tid & 63;
  const int wid  = tid >> 6;                       // 0..7
  const int bid  = blockIdx.x;
  const int row  = bid * WAVES + wid;              // this wave's row

  __shared__ float2   smemV[DIM];                  // 8KB staged vector
  __shared__ float2   smemPub[WAVES];              // block's 8 published elems
  __shared__ float    red[WAVES];
  __shared__ unsigned wdone;                       // monotone publish counter
  __shared__ unsigned ready;                       // monotone wake word
  float* smemVf   = (float*)smemV;                 // word W holds float W
  float* smemPubF = (float*)smemPub;

  // ---- gate-0 G row first: HBM latency overlaps the norm phase ----
  float a[16];
  {
    const float* Gr = gens + (size_t)row * DIM;
    #pragma unroll
    for (int p = 0; p < 16; ++p) a[p] = Gr[p * 64 + lane];
  }

  if (tid == 0) { wdone = 0; ready = 0; }
  {
    float f0 = feat[tid], f1 = feat[tid + TPB];
    float s = f0 * f0 + f1 * f1;
    #pragma unroll
    for (int mm = 1; mm < 64; mm <<= 1) s += __shfl_xor(s, mm);
    if (lane == 0) red[wid] = s;
  }
  __syncthreads();                                  // init only
  float tot = 0.f;
  #pragma unroll
  for (int i = 0; i < WAVES; ++i) tot += red[i];
  const float inv = 1.0f / sqrtf(tot);

  float pr = feat[row] * inv;
  float pi = 0.f;

  unsigned pub = 0;   // completed publishes (lock-stepped across all waves/blocks)
  bool  pend_anext = false;                        // wave0: deferred next-gate G
  int   gnext = 0;
  float anext[16];

  // publish: LDS aggregate; block's last publisher fans the 128B segment
  // out as ONE coalesced store (lanes 0..15, one u64 each). Fire-and-forget.
  auto publish = [&](float sr, float si) {
    if (lane == 0) smemPub[wid] = make_float2(sr, si);
    asm volatile("s_waitcnt lgkmcnt(0)" ::: "memory");  // ds_write retired
    unsigned old = 0;
    if (lane == 0) old = atomicAdd(&wdone, 1u);     // LDS, monotone
    old = __shfl(old, 0);
    const unsigned seq = pub + 1;
    if (old == WAVES * seq - 1) {                   // block's last publisher
      u64* dst = (seq & 1) ? vbuf1 : vbuf0;
      if (lane < SEGW) {
        const float f = smemPubF[lane];             // all 8 writes visible
        __hip_atomic_store(dst + bid * SEGW + lane, packw(f, seq),
                           __ATOMIC_RELAXED, __HIP_MEMORY_SCOPE_AGENT);
      }
    }
    ++pub;
  };

  auto issue_anext = [&]() {                        // wave0's deferred G row
    const float* Gr = gens + (size_t)gnext * DIM * DIM + (size_t)row * DIM;
    #pragma unroll
    for (int p = 0; p < 16; ++p) anext[p] = Gr[p * 64 + lane];
    pend_anext = false;
  };

  for (int g = 0; g < NG; ++g) {
    // ---- Chebyshev coefficients: J_k(|z|), downward Miller in fp64 ----
    const float  th = theta[g];
    const double z  = (double)th * (double)SCALE;
    const double az = fmax(fabs(z), 1e-6);
    const float  sg = (th < 0.f) ? -1.f : 1.f;      // J_k(z)=sg^k J_k(|z|)

    double bv[19];
    bv[18] = 1e-30;
    bv[17] = (36.0 / az) * 1e-30;
    #pragma unroll
    for (int k = 17; k >= 1; --k)
      bv[k - 1] = (2.0 * (double)k / az) * bv[k] - bv[k + 1];
    double S = bv[0];
    #pragma unroll
    for (int k = 2; k <= 18; k += 2) S += 2.0 * bv[k];
    const double invS = 1.0 / S;

    float jc[KMAX + 2];
    #pragma unroll
    for (int k = 0; k <= KMAX + 1; ++k) jc[k] = (float)(bv[k] * invS);

    int m = KMAX; bool found = false;
    #pragma unroll
    for (int k = 1; k <= KMAX; ++k) {
      if (!found && (double)(k + 1) > az &&
          fabs(bv[k + 1] * invS) < (double)CTOL) { m = k; found = true; }
    }
    // m identical on every wave/block -> uniform phase count

    float accr = jc[0] * pr, acci = jc[0] * pi;
    float wm1r = pr, wm1i = pi, wm2r = 0.f, wm2i = 0.f;

    #pragma unroll
    for (int k = 1; k <= KMAX; ++k) {               // fully unrolled
      if (k > m) break;

      // ---- consume full w_{k-1} ----
      float2 v[16];
      if (g == 0 && k == 1) {
        // psi_0 rebuilt locally: no publish/wait phase needed
        #pragma unroll
        for (int p = 0; p < 16; ++p)
          v[p] = make_float2(feat[p * 64 + lane] * inv, 0.f);
      } else {
        if (wid == 0) {
          // poll = detect + data load in one: 32 words/lane over 128 segs
          const u64* vsrc = (pub & 1) ? vbuf1 : vbuf0;
          for (;;) {
            u64 x[32];
            #pragma unroll
            for (int c = 0; c < 32; ++c)
              x[c] = __hip_atomic_load(vsrc + c * 64 + lane,
                                       __ATOMIC_RELAXED, __HIP_MEMORY_SCOPE_AGENT);
            bool ok = true;
            #pragma unroll
            for (int c = 0; c < 32; ++c)
              ok = ok && ((unsigned)(x[c] >> 32) == pub);
            if (__all(ok)) {
              // word order == smemVf float order (layout identity, see notes)
              #pragma unroll
              for (int c = 0; c < 32; ++c) smemVf[c * 64 + lane] = unpackf(x[c]);
              break;
            }
            __builtin_amdgcn_s_sleep(2);            // ~128cy backoff
          }
          // release orders the ds_writes before the wake word
          __hip_atomic_store(&ready, pub, __ATOMIC_RELEASE,
                             __HIP_MEMORY_SCOPE_WORKGROUP);
          if (pend_anext) issue_anext();            // drains under matvec+poll
          #pragma unroll
          for (int p = 0; p < 16; ++p) v[p] = smemV[p * 64 + lane];
        } else {
          while ((int)(__hip_atomic_load(&ready, __ATOMIC_ACQUIRE,
                                         __HIP_MEMORY_SCOPE_WORKGROUP) - pub) < 0) {
            __builtin_amdgcn_s_sleep(1);            // ~64cy backoff
          }
          #pragma unroll
          for (int p = 0; p < 16; ++p) v[p] = smemV[p * 64 + lane];
        }
      }

      // ---- y = G * w_{k-1} (own row) ----
      float yr = 0.f, yi = 0.f;
      #pragma unroll
      for (int p = 0; p < 16; ++p) {
        yr = fmaf(a[p], v[p].x, yr);
        yi = fmaf(a[p], v[p].y, yi);
      }
      #pragma unroll
      for (int mm = 1; mm < 64; mm <<= 1) {
        yr += __shfl_xor(yr, mm);
        yi += __shfl_xor(yi, mm);
      }

      // ---- w_k = (k==1) ? xh*w_0 : 2*xh*w_{k-1} - w_{k-2} ----
      const float ur = yr * INVSCALE;
      const float ui = yi * INVSCALE;
      const float wkr = (k == 1) ? ur : fmaf(2.f, ur, -wm2r);
      const float wki = (k == 1) ? ui : fmaf(2.f, ui, -wm2i);

      const bool last = (k == m);
      if (!last) publish(wkr, wki);     // ~150cy LDS fan-in, no RTT on our side

      // ---- acc += c_k * w_k,  c_k = 2*(-i*sg)^k * J_k(|z|) ----
      {
        const float j2  = 2.f * jc[k];              // register (constant k)
        const float sj2 = sg * j2;
        if ((k & 3) == 0) {
          accr = fmaf(j2, wkr, accr);
          acci = fmaf(j2, wki, acci);
        } else if ((k & 3) == 1) {
          accr = fmaf( sj2, wki, accr);
          acci = fmaf(-sj2, wkr, acci);
        } else if ((k & 3) == 2) {
          accr = fmaf(-j2, wkr, accr);
          acci = fmaf(-j2, wki, acci);
        } else {
          accr = fmaf(-sj2, wki, accr);
          acci = fmaf( sj2, wkr, acci);
        }
      }

      // ---- next gate's G row: waves 1-7 issue now (no VMEM conflicts);
      // wave0 defers past its next poll (vmcnt retires in issue order) ----
      if (k == 1 && g < NG - 1) {
        if (wid != 0) {
          const float* Gr = gens + (size_t)(g + 1) * DIM * DIM
                                 + (size_t)row * DIM;
          #pragma unroll
          for (int p = 0; p < 16; ++p) anext[p] = Gr[p * 64 + lane];
        } else {
          pend_anext = true; gnext = g + 1;
        }
      }

      if (last) {
        if (g < NG - 1) publish(accr, acci);        // psi_{g+1}
      } else {
        wm2r = wm1r; wm2i = wm1i;
        wm1r = wkr;  wm1i = wki;
      }
    }

    if (g < NG - 1) {
      if (wid == 0 && pend_anext) issue_anext();    // m==1 edge: no wait came
      #pragma unroll
      for (int p = 0; p < 16; ++p) a[p] = anext[p]; // swap in next gate's row
    }
    pr = accr; pi = acci;
  }

  if (lane == 0) out[row] = pr * pr + pi * pi;
}

extern "C" void kernel_launch(void* const* d_in, const int* in_sizes, int n_in,
                              void* d_out, int out_size, void* d_ws, size_t ws_size,
                              hipStream_t stream) {
  const float* feat  = (const float*)d_in[0];
  const float* theta = (const float*)d_in[1];
  const float* gens  = (const float*)d_in[2];
  float* out = (float*)d_out;

  // layout: vbuf0 (2048 u64 = 16KB) | vbuf1 (16KB) = 32KB. No flags array.
  // No memset: embedded seq never matches the 0xAAAAAAAA workspace poison.
  u64* vbuf0 = (u64*)d_ws;
  u64* vbuf1 = (u64*)((char*)d_ws + (size_t)DIM * 2 * sizeof(u64));

  qsim_kernel<<<dim3(NBLK), dim3(TPB), 0, stream>>>(
      feat, theta, gens, out, vbuf0, vbuf1);
}

// Round 9
// 140.903 us; speedup vs baseline: 1.1038x; 1.0235x over previous
//
#include <hip/hip_runtime.h>

#define DIM   1024
#define NG    8
#define NBLK  256                 // R19: one block per CU
#define TPB   256                 // 4 waves/block
#define WAVES (TPB / 64)          // 4
#define SCALE    1.45f            // upper bound on spectral radius (semicircle ~1.414)
#define INVSCALE (1.0f / SCALE)
#define CTOL  5e-3f               // same truncation (absmax 9.155e-5, stable tripwire)
#define KMAX  12
#define SEGW  (2 * WAVES)         // 8 u64 words per block segment (64B = ONE line)

typedef unsigned long long u64;

// R19 = R18 protocol byte-identical (LDS fan-in publish, closer stores the
// seq-embedded segment fire-and-forget, wave0 poll IS the data load, LDS
// relay), geometry pushed to one-block-per-CU. R18 post-mortem: removing the
// ack+flag RTTs moved dispatch only ~2us -> those were already overlapped;
// the remaining per-phase cost is (a) intra-block fan-in (wake spread + 8
// serialized wdone atomics + slowest-of-8 closer), (b) detect sampling lag,
// (c) max-over-blocks jitter; plus the per-CU G term R13 proved cuttable.
// This round:
//  (1) WAVES 8 -> 4: fan-in, wake spread, closer-lag all ~halve.
//  (2) NBLK 128 -> 256: per-CU G halves (16KB/gate) -- the R13 lever again.
//  (3) segment = exactly one 64B line; sweep SHAPE unchanged (256 segs x 8
//      words = 2048 words = 32/lane -- same traffic as R18).
// Concentration discipline kept: ONE wave per block polls, read-only, with
// s_sleep(2) backoff. WAR safety: same seq-carried induction as R18 (block
// stores phase p+1 only after consuming p, which requires every block's
// segment p committed, which post-dates all smemPub/smemV reads of p-1).
// Poison 0xAAAAAAAA never matches a real seq; harness re-poisons per iter.

__device__ __forceinline__ u64 packw(float v, unsigned seq) {
  union { float f; unsigned u; } c; c.f = v;
  return ((u64)seq << 32) | (u64)c.u;
}
__device__ __forceinline__ float unpackf(u64 x) {
  union { unsigned u; float f; } c; c.u = (unsigned)x;
  return c.f;
}

__global__ __launch_bounds__(TPB) void qsim_kernel(
    const float* __restrict__ feat,
    const float* __restrict__ theta,
    const float* __restrict__ gens,
    float*       __restrict__ out,
    u64*         __restrict__ vbuf0,
    u64*         __restrict__ vbuf1)
{
  const int tid  = threadIdx.x;
  const int lane = tid & 63;
  const int wid  = tid >> 6;                       // 0..3
  const int bid  = blockIdx.x;
  const int row  = bid * WAVES + wid;              // this wave's row

  __shared__ float2   smemV[DIM];                  // 8KB staged vector
  __shared__ float2   smemPub[WAVES];              // block's 4 published elems
  __shared__ float    red[WAVES];
  __shared__ unsigned wdone;                       // monotone publish counter
  __shared__ unsigned ready;                       // monotone wake word
  float* smemVf   = (float*)smemV;                 // word W holds float W
  float* smemPubF = (float*)smemPub;

  // ---- gate-0 G row first: HBM latency overlaps the norm phase ----
  float a[16];
  {
    const float* Gr = gens + (size_t)row * DIM;
    #pragma unroll
    for (int p = 0; p < 16; ++p) a[p] = Gr[p * 64 + lane];
  }

  if (tid == 0) { wdone = 0; ready = 0; }
  {
    float f0 = feat[tid],           f1 = feat[tid + TPB];
    float f2 = feat[tid + 2 * TPB], f3 = feat[tid + 3 * TPB];
    float s = f0 * f0 + f1 * f1 + f2 * f2 + f3 * f3;
    #pragma unroll
    for (int mm = 1; mm < 64; mm <<= 1) s += __shfl_xor(s, mm);
    if (lane == 0) red[wid] = s;
  }
  __syncthreads();                                  // init only
  float tot = 0.f;
  #pragma unroll
  for (int i = 0; i < WAVES; ++i) tot += red[i];
  const float inv = 1.0f / sqrtf(tot);

  float pr = feat[row] * inv;
  float pi = 0.f;

  unsigned pub = 0;   // completed publishes (lock-stepped across all waves/blocks)
  bool  pend_anext = false;                        // wave0: deferred next-gate G
  int   gnext = 0;
  float anext[16];

  // publish: LDS aggregate; block's last publisher fans the 64B segment out
  // as ONE coalesced store (lanes 0..7, one u64 each). Fire-and-forget.
  auto publish = [&](float sr, float si) {
    if (lane == 0) smemPub[wid] = make_float2(sr, si);
    asm volatile("s_waitcnt lgkmcnt(0)" ::: "memory");  // ds_write retired
    unsigned old = 0;
    if (lane == 0) old = atomicAdd(&wdone, 1u);     // LDS, monotone
    old = __shfl(old, 0);
    const unsigned seq = pub + 1;
    if (old == WAVES * seq - 1) {                   // block's last publisher
      u64* dst = (seq & 1) ? vbuf1 : vbuf0;
      if (lane < SEGW) {
        const float f = smemPubF[lane];             // all 4 writes visible
        __hip_atomic_store(dst + bid * SEGW + lane, packw(f, seq),
                           __ATOMIC_RELAXED, __HIP_MEMORY_SCOPE_AGENT);
      }
    }
    ++pub;
  };

  auto issue_anext = [&]() {                        // wave0's deferred G row
    const float* Gr = gens + (size_t)gnext * DIM * DIM + (size_t)row * DIM;
    #pragma unroll
    for (int p = 0; p < 16; ++p) anext[p] = Gr[p * 64 + lane];
    pend_anext = false;
  };

  for (int g = 0; g < NG; ++g) {
    // ---- Chebyshev coefficients: J_k(|z|), downward Miller in fp64 ----
    const float  th = theta[g];
    const double z  = (double)th * (double)SCALE;
    const double az = fmax(fabs(z), 1e-6);
    const float  sg = (th < 0.f) ? -1.f : 1.f;      // J_k(z)=sg^k J_k(|z|)

    double bv[19];
    bv[18] = 1e-30;
    bv[17] = (36.0 / az) * 1e-30;
    #pragma unroll
    for (int k = 17; k >= 1; --k)
      bv[k - 1] = (2.0 * (double)k / az) * bv[k] - bv[k + 1];
    double S = bv[0];
    #pragma unroll
    for (int k = 2; k <= 18; k += 2) S += 2.0 * bv[k];
    const double invS = 1.0 / S;

    float jc[KMAX + 2];
    #pragma unroll
    for (int k = 0; k <= KMAX + 1; ++k) jc[k] = (float)(bv[k] * invS);

    int m = KMAX; bool found = false;
    #pragma unroll
    for (int k = 1; k <= KMAX; ++k) {
      if (!found && (double)(k + 1) > az &&
          fabs(bv[k + 1] * invS) < (double)CTOL) { m = k; found = true; }
    }
    // m identical on every wave/block -> uniform phase count

    float accr = jc[0] * pr, acci = jc[0] * pi;
    float wm1r = pr, wm1i = pi, wm2r = 0.f, wm2i = 0.f;

    #pragma unroll
    for (int k = 1; k <= KMAX; ++k) {               // fully unrolled
      if (k > m) break;

      // ---- consume full w_{k-1} ----
      float2 v[16];
      if (g == 0 && k == 1) {
        // psi_0 rebuilt locally: no publish/wait phase needed
        #pragma unroll
        for (int p = 0; p < 16; ++p)
          v[p] = make_float2(feat[p * 64 + lane] * inv, 0.f);
      } else {
        if (wid == 0) {
          // poll = detect + data load in one: 32 words/lane over 256 segs
          const u64* vsrc = (pub & 1) ? vbuf1 : vbuf0;
          for (;;) {
            u64 x[32];
            #pragma unroll
            for (int c = 0; c < 32; ++c)
              x[c] = __hip_atomic_load(vsrc + c * 64 + lane,
                                       __ATOMIC_RELAXED, __HIP_MEMORY_SCOPE_AGENT);
            bool ok = true;
            #pragma unroll
            for (int c = 0; c < 32; ++c)
              ok = ok && ((unsigned)(x[c] >> 32) == pub);
            if (__all(ok)) {
              // word order == smemVf float order (layout identity)
              #pragma unroll
              for (int c = 0; c < 32; ++c) smemVf[c * 64 + lane] = unpackf(x[c]);
              break;
            }
            __builtin_amdgcn_s_sleep(2);            // ~128cy backoff
          }
          // release orders the ds_writes before the wake word
          __hip_atomic_store(&ready, pub, __ATOMIC_RELEASE,
                             __HIP_MEMORY_SCOPE_WORKGROUP);
          if (pend_anext) issue_anext();            // drains under matvec+poll
          #pragma unroll
          for (int p = 0; p < 16; ++p) v[p] = smemV[p * 64 + lane];
        } else {
          while ((int)(__hip_atomic_load(&ready, __ATOMIC_ACQUIRE,
                                         __HIP_MEMORY_SCOPE_WORKGROUP) - pub) < 0) {
            __builtin_amdgcn_s_sleep(1);            // ~64cy backoff
          }
          #pragma unroll
          for (int p = 0; p < 16; ++p) v[p] = smemV[p * 64 + lane];
        }
      }

      // ---- y = G * w_{k-1} (own row) ----
      float yr = 0.f, yi = 0.f;
      #pragma unroll
      for (int p = 0; p < 16; ++p) {
        yr = fmaf(a[p], v[p].x, yr);
        yi = fmaf(a[p], v[p].y, yi);
      }
      #pragma unroll
      for (int mm = 1; mm < 64; mm <<= 1) {
        yr += __shfl_xor(yr, mm);
        yi += __shfl_xor(yi, mm);
      }

      // ---- w_k = (k==1) ? xh*w_0 : 2*xh*w_{k-1} - w_{k-2} ----
      const float ur = yr * INVSCALE;
      const float ui = yi * INVSCALE;
      const float wkr = (k == 1) ? ur : fmaf(2.f, ur, -wm2r);
      const float wki = (k == 1) ? ui : fmaf(2.f, ui, -wm2i);

      const bool last = (k == m);
      if (!last) publish(wkr, wki);     // ~150cy LDS fan-in, no RTT on our side

      // ---- acc += c_k * w_k,  c_k = 2*(-i*sg)^k * J_k(|z|) ----
      {
        const float j2  = 2.f * jc[k];              // register (constant k)
        const float sj2 = sg * j2;
        if ((k & 3) == 0) {
          accr = fmaf(j2, wkr, accr);
          acci = fmaf(j2, wki, acci);
        } else if ((k & 3) == 1) {
          accr = fmaf( sj2, wki, accr);
          acci = fmaf(-sj2, wkr, acci);
        } else if ((k & 3) == 2) {
          accr = fmaf(-j2, wkr, accr);
          acci = fmaf(-j2, wki, acci);
        } else {
          accr = fmaf(-sj2, wki, accr);
          acci = fmaf( sj2, wkr, acci);
        }
      }

      // ---- next gate's G row: waves 1-3 issue now (no VMEM conflicts);
      // wave0 defers past its next poll (vmcnt retires in issue order) ----
      if (k == 1 && g < NG - 1) {
        if (wid != 0) {
          const float* Gr = gens + (size_t)(g + 1) * DIM * DIM
                                 + (size_t)row * DIM;
          #pragma unroll
          for (int p = 0; p < 16; ++p) anext[p] = Gr[p * 64 + lane];
        } else {
          pend_anext = true; gnext = g + 1;
        }
      }

      if (last) {
        if (g < NG - 1) publish(accr, acci);        // psi_{g+1}
      } else {
        wm2r = wm1r; wm2i = wm1i;
        wm1r = wkr;  wm1i = wki;
      }
    }

    if (g < NG - 1) {
      if (wid == 0 && pend_anext) issue_anext();    // m==1 edge: no wait came
      #pragma unroll
      for (int p = 0; p < 16; ++p) a[p] = anext[p]; // swap in next gate's row
    }
    pr = accr; pi = acci;
  }

  if (lane == 0) out[row] = pr * pr + pi * pi;
}

extern "C" void kernel_launch(void* const* d_in, const int* in_sizes, int n_in,
                              void* d_out, int out_size, void* d_ws, size_t ws_size,
                              hipStream_t stream) {
  const float* feat  = (const float*)d_in[0];
  const float* theta = (const float*)d_in[1];
  const float* gens  = (const float*)d_in[2];
  float* out = (float*)d_out;

  // layout: vbuf0 (2048 u64 = 16KB) | vbuf1 (16KB) = 32KB. No flags array.
  // No memset: embedded seq never matches the 0xAAAAAAAA workspace poison.
  u64* vbuf0 = (u64*)d_ws;
  u64* vbuf1 = (u64*)((char*)d_ws + (size_t)DIM * 2 * sizeof(u64));

  qsim_kernel<<<dim3(NBLK), dim3(TPB), 0, stream>>>(
      feat, theta, gens, out, vbuf0, vbuf1);
}